// Round 8
// baseline (411.987 us; speedup 1.0000x reference)
//
#include <hip/hip_runtime.h>
#include <math.h>

// Problem constants: B=64/side (128 concat), d=256, C=128, S=1024, TEMP=0.1, COEFF=0.5
#define TEMP_INV 10.0f

typedef unsigned long long u64;
typedef __attribute__((ext_vector_type(8))) __bf16 bf16x8;
typedef __attribute__((ext_vector_type(4))) float f32x4;

// Monotone u32 key: fkey(a) > fkey(b) iff a > b (floats, no NaN).
__device__ inline unsigned fkey(float v) {
  unsigned u = __float_as_uint(v);
  return (u & 0x80000000u) ? ~u : (u | 0x80000000u);
}

// async global->LDS, 16B per lane (wave-uniform base + lane*16 ordering).
__device__ __forceinline__ void async_copy16(const void* gp, void* lp) {
  __builtin_amdgcn_global_load_lds(
      (__attribute__((address_space(1))) void*)(unsigned long long)gp,
      (__attribute__((address_space(3))) void*)(unsigned long long)lp,
      16, 0, 0);
}

// ---------- kcvt: fused transpose + bf16 convert + norms ----------
// R8: XCD-aligned block mapping co-designed with ksim's affinity: b and b+64
// written by blocks on XCD b%8 (h&7), pairs (j>>1) interleaved Q/K (j&1) so
// the freshest L2-dirty pair is the one ksim reads first. Inner structure =
// R7 single-latency version (32 loads up front, one barrier). Bit-identical.
__global__ __launch_bounds__(256) void kcvt(const float* __restrict__ ofq,
                                            const float* __restrict__ ofk,
                                            __bf16* __restrict__ ofT,
                                            float* __restrict__ of_invn) {
  unsigned bx = blockIdx.x;
  int t = threadIdx.x;
  int xcd = bx & 7;
  unsigned idx = bx >> 3;       // 0..511 within XCD
  int j = idx >> 5;             // 0..15: pair (j>>1), side (j&1)
  int s0 = (idx & 31) * 32;
  int b = xcd + 8 * (j >> 1) + 64 * (j & 1);
  const float* src = (b < 64) ? (ofq + (size_t)b * 262144) : (ofk + (size_t)(b - 64) * 262144);
  __shared__ __bf16 T[8][32][36];  // per-iteration tiles, no reuse hazard
  __shared__ float R[8][32];
  int dd = t >> 5, ss = t & 31;
  int wr = t >> 3, wd = t & 7;
  float v[8][4];
  // phase 0: all 32 independent loads in flight
#pragma unroll
  for (int d0i = 0; d0i < 8; ++d0i)
#pragma unroll
    for (int it = 0; it < 4; ++it)
      v[d0i][it] = src[(size_t)(d0i * 32 + dd + 8 * it) * 1024 + s0 + ss];
  // ssq in the exact original order (d0 asc, it asc)
  float ssq = 0.f;
#pragma unroll
  for (int d0i = 0; d0i < 8; ++d0i)
#pragma unroll
    for (int it = 0; it < 4; ++it) ssq += v[d0i][it] * v[d0i][it];
  // phase 1: all transpose tiles + norm partials into LDS
#pragma unroll
  for (int d0i = 0; d0i < 8; ++d0i)
#pragma unroll
    for (int it = 0; it < 4; ++it) T[d0i][ss][dd + 8 * it] = (__bf16)v[d0i][it];
  R[dd][ss] = ssq;
  __syncthreads();  // the only barrier
  // phase 2: all output writes
  __bf16* out = ofT + (size_t)b * 262144 + (size_t)s0 * 256;
#pragma unroll
  for (int d0i = 0; d0i < 8; ++d0i)
    *(uint2*)(out + (size_t)wr * 256 + d0i * 32 + wd * 4) = *(const uint2*)(&T[d0i][wr][wd * 4]);
  if (t < 32) {
    float a = 0.f;
#pragma unroll
    for (int r = 0; r < 8; ++r) a += R[r][t];
    of_invn[b * 1024 + s0 + t] = 1.0f / fmaxf(sqrtf(a), 1e-12f);
  }
}

// ---------- kpre2: x-norms + ad transpose + global loss (independent of ksim) ----------
__global__ __launch_bounds__(256) void kpre2(
    const float* __restrict__ xq, const float* __restrict__ xk,
    float* __restrict__ x_invn,
    const float* __restrict__ adq, const float* __restrict__ adk,
    float* __restrict__ adt,
    const float* __restrict__ agq, const float* __restrict__ agk,
    float* __restrict__ gsum) {
  unsigned bx = blockIdx.x;
  int t = threadIdx.x;
  if (bx < 512) {
    int idx = bx * 256 + t;  // 0..131071
    int b = idx >> 10, s = idx & 1023;
    const float* src = (b < 64) ? (xq + (size_t)b * 131072) : (xk + (size_t)(b - 64) * 131072);
    float acc = 0.f;
#pragma unroll 8
    for (int c = 0; c < 128; ++c) { float v = src[c * 1024 + s]; acc += v * v; }
    x_invn[idx] = 1.0f / fmaxf(sqrtf(acc), 1e-12f);
  } else if (bx < 576) {
    int i = (bx - 512) * 256 + t;  // 0..16383
    int dir = i >> 13, r = i & 8191;
    int jj = r >> 7, c = r & 127;
    const float* ad = dir == 0 ? adk : adq;
    adt[dir * 8192 + c * 64 + jj] = ad[jj * 128 + c];
  } else {
    // kglobal: 2 rows i per block (t<128 -> i0, t>=128 -> i0+1)
    __shared__ float logits[2][128];
    __shared__ float rinv[128];
    int ii = t >> 7, jl = t & 127;
    int i = (int)(bx - 576) * 2 + ii;
    const float* rowi = (i < 64) ? (agq + i * 128) : (agk + (i - 64) * 128);
    const float* rowj = (jl < 64) ? (agq + jl * 128) : (agk + (jl - 64) * 128);
    float dot = 0.f, nj = 0.f;
#pragma unroll 8
    for (int c = 0; c < 128; ++c) { float a = rowi[c], bb = rowj[c]; dot += a * bb; nj += bb * bb; }
    if (ii == 0) rinv[jl] = 1.0f / fmaxf(sqrtf(nj), 1e-12f);
    __syncthreads();
    logits[ii][jl] = dot * rinv[i] * rinv[jl] * TEMP_INV;
    __syncthreads();
    if (jl == 0) {
      int pos = (i + 64) & 127;
      float m = -INFINITY;
      for (int tt = 0; tt < 128; ++tt) if (tt != i) m = fmaxf(m, logits[ii][tt]);
      float e = 0.f;
      for (int tt = 0; tt < 128; ++tt) if (tt != i) e += __expf(logits[ii][tt] - m);
      atomicAdd(gsum, m + __logf(e) - logits[ii][pos]);
    }
  }
}

// ---------- MFMA sim GEMM + dual argmax ----------
// 256x256 tile, 8 waves (2M x 4N), BK=64, double-buffered, G4 XOR-swizzled LDS,
// b<->XCD affinity; R8: b iterated in REVERSE so the first resident blocks read
// the freshest (still-L2-dirty) kcvt output pairs.
__global__ __launch_bounds__(512, 2) void ksim(
    const __bf16* __restrict__ ofT, const float* __restrict__ of_invn,
    u64* __restrict__ best_row, u64* __restrict__ best_col) {
  // hardware linear block id -> (xcd, slot); b % 8 == xcd; 1024 = 8 XCD x 128
  unsigned h = blockIdx.x + (blockIdx.y << 2) + (blockIdx.z << 4);
  int xcd = h & 7;
  unsigned slot = h >> 3;                       // 0..127 within XCD
  int b = xcd + 8 * (7 - (int)(slot >> 4));     // reverse freshness order
  int tile = slot & 15;
  int s0 = (tile & 3) * 256, t0 = (tile >> 2) * 256;

  const __bf16* Ag = ofT + (size_t)b * 262144;        // q rows [1024][256]
  const __bf16* Bg = ofT + (size_t)(b + 64) * 262144; // k rows
  __shared__ __bf16 As[2][16384];  // 64 KiB
  __shared__ __bf16 Bs[2][16384];  // 64 KiB  (total 128 KiB)

  int t = threadIdx.x;
  int lane = t & 63, w = t >> 6;
  int lc = lane & 15, q = lane >> 4;
  int wm = w >> 2, wn = w & 3;  // 2 x 4 wave grid; wave owns 128(M) x 64(N)

  f32x4 acc[8][4];
#pragma unroll
  for (int i = 0; i < 8; ++i)
#pragma unroll
    for (int j = 0; j < 4; ++j) acc[i][j] = (f32x4)(0.f);

  // fragment LDS offsets (bf16 units), kk=0; kk=1 reads offset ^ 32
  int aoff[8], boff[4];
#pragma unroll
  for (int i = 0; i < 8; ++i) {
    int mr = wm * 128 + i * 16 + lc;
    aoff[i] = mr * 64 + ((q ^ (mr & 7)) << 3);
  }
#pragma unroll
  for (int j = 0; j < 4; ++j) {
    int nc = wn * 64 + j * 16 + lc;
    boff[j] = nc * 64 + ((q ^ (nc & 7)) << 3);
  }

  // staging: thread t, chunk c: row m = c*64 + (t>>3), phys slot g = t&7,
  // logical group lg = g ^ (m&7) = g ^ ((t>>3)&7)  (c*64 is 0 mod 8)
  int ms = t >> 3, gphys = t & 7;
  int lg = gphys ^ (ms & 7);
  size_t aSrc = (size_t)(s0 + ms) * 256 + lg * 8;
  size_t bSrc = (size_t)(t0 + ms) * 256 + lg * 8;

  auto STAGE = [&](int bufn, int k0) {
    char* aL = (char*)&As[bufn][0] + t * 16;
    char* bL = (char*)&Bs[bufn][0] + t * 16;
#pragma unroll
    for (int c = 0; c < 4; ++c) {
      async_copy16(Ag + aSrc + (size_t)c * 16384 + k0, aL + c * 8192);
      async_copy16(Bg + bSrc + (size_t)c * 16384 + k0, bL + c * 8192);
    }
  };

  // prologue: stage k0=0 into buf 0
  STAGE(0, 0);
  __syncthreads();

  for (int it = 0; it < 4; ++it) {
    int buf = it & 1;
    if (it < 3) STAGE(buf ^ 1, (it + 1) * 64);
#pragma unroll
    for (int kk = 0; kk < 2; ++kk) {
      int kx = kk << 5;  // ^32 toggles phys k-group bit 2
      bf16x8 af[8], bfr[4];
#pragma unroll
      for (int i = 0; i < 8; ++i) af[i] = *(const bf16x8*)(&As[buf][0] + (aoff[i] ^ kx));
#pragma unroll
      for (int j = 0; j < 4; ++j) bfr[j] = *(const bf16x8*)(&Bs[buf][0] + (boff[j] ^ kx));
      __builtin_amdgcn_s_setprio(1);
#pragma unroll
      for (int i = 0; i < 8; ++i)
#pragma unroll
        for (int j = 0; j < 4; ++j)
          acc[i][j] = __builtin_amdgcn_mfma_f32_16x16x32_bf16(af[i], bfr[j], acc[i][j], 0, 0, 0);
      __builtin_amdgcn_s_setprio(0);
    }
    __syncthreads();  // readers done with buf + drains prefetch vmcnt
  }

  // ---- epilogue (f32 domain). C/D layout: col=lane&15, row=(lane>>4)*4+reg ----
  float sk[4];
#pragma unroll
  for (int j = 0; j < 4; ++j) sk[j] = of_invn[65536 + b * 1024 + t0 + wn * 64 + j * 16 + lc];
  float sq[32];
#pragma unroll
  for (int i = 0; i < 8; ++i)
#pragma unroll
    for (int e = 0; e < 4; ++e)
      sq[i * 4 + e] = of_invn[b * 1024 + s0 + wm * 128 + i * 16 + q * 4 + e];

  u64* browb = best_row + (size_t)b * 1024 + s0;
  u64* bcolb = best_col + (size_t)b * 1024 + t0;

  // row direction: argmax over t for fixed s (scale by sik only; siq>0 dropped)
#pragma unroll
  for (int i = 0; i < 8; ++i) {
#pragma unroll
    for (int e = 0; e < 4; ++e) {
      float v[4];
#pragma unroll
      for (int j = 0; j < 4; ++j) v[j] = acc[i][j][e] * sk[j];
      float vb = fmaxf(fmaxf(v[0], v[1]), fmaxf(v[2], v[3]));
#pragma unroll
      for (int mask = 1; mask <= 8; mask <<= 1) vb = fmaxf(vb, __shfl_xor(vb, mask));
      unsigned ib = 0xFFFFFFFFu;
#pragma unroll
      for (int j = 0; j < 4; ++j) {
        unsigned cand = (v[j] == vb) ? (unsigned)(t0 + wn * 64 + j * 16 + lc) : 0xFFFFFFFFu;
        ib = min(ib, cand);
      }
#pragma unroll
      for (int mask = 1; mask <= 8; mask <<= 1) ib = min(ib, __shfl_xor(ib, mask));
      if (lc == 0)
        atomicMax(browb + wm * 128 + i * 16 + q * 4 + e,
                  ((u64)fkey(vb) << 32) | (u64)(0xFFFFFFFFu - ib));
    }
  }

  // col direction: argmax over s for fixed t (scale by siq only)
#pragma unroll
  for (int j = 0; j < 4; ++j) {
    float cb = -INFINITY;
#pragma unroll
    for (int i = 0; i < 8; ++i)
#pragma unroll
      for (int e = 0; e < 4; ++e) cb = fmaxf(cb, acc[i][j][e] * sq[i * 4 + e]);
    cb = fmaxf(cb, __shfl_xor(cb, 16));
    cb = fmaxf(cb, __shfl_xor(cb, 32));
    unsigned ib = 0xFFFFFFFFu;
#pragma unroll
    for (int i = 0; i < 8; ++i)
#pragma unroll
      for (int e = 0; e < 4; ++e) {
        float m2 = acc[i][j][e] * sq[i * 4 + e];  // bitwise-identical recompute
        unsigned cand = (m2 == cb) ? (unsigned)(s0 + wm * 128 + i * 16 + q * 4 + e) : 0xFFFFFFFFu;
        ib = min(ib, cand);
      }
    ib = min(ib, __shfl_xor(ib, 16));
    ib = min(ib, __shfl_xor(ib, 32));
    if (lane < 16)
      atomicMax(bcolb + wn * 64 + j * 16 + lane,
                ((u64)fkey(cb) << 32) | (u64)(0xFFFFFFFFu - ib));
  }
}

// ---------- pos logits ----------
// R8: s split across 2 blocks (grid 64x2x2, 512 thr) -> 256 blocks = full GPU.
// Per-s math order unchanged vs R5.
__global__ __launch_bounds__(512) void kpos(
    const float* __restrict__ xq, const float* __restrict__ xk,
    const float* __restrict__ x_invn,
    const u64* __restrict__ best_row, const u64* __restrict__ best_col,
    float* __restrict__ posl) {
  int b = blockIdx.x, dir = blockIdx.y, half = blockIdx.z;
  const float* xsrc = dir == 0 ? xq : xk;
  const float* xdst = dir == 0 ? xk : xq;
  const float* inv_src = x_invn + (dir ? 65536 : 0);
  const float* inv_dst = x_invn + (dir ? 0 : 65536);
  const u64* best = dir == 0 ? best_row : best_col;

  __shared__ float xrow[8][1024];  // 32KB
  __shared__ float sdinv[1024];    // 4KB
  int t = threadIdx.x;             // 0..511
  int s = half * 512 + t;
  sdinv[t] = inv_dst[b * 1024 + t];
  sdinv[t + 512] = inv_dst[b * 1024 + t + 512];
  u64 p = best[(size_t)b * 1024 + s];
  int sidx = (int)(0xFFFFFFFFu - (unsigned)(p & 0xFFFFFFFFull));
  const float* xsb = xsrc + (size_t)b * 131072;
  const float* xdb = xdst + (size_t)b * 131072;
  float acc = 0.f;
  for (int c0 = 0; c0 < 128; c0 += 8) {
    __syncthreads();
#pragma unroll
    for (int qq = 0; qq < 4; ++qq)
      ((float4*)xrow)[t + 512 * qq] = ((const float4*)(xdb + (size_t)c0 * 1024))[t + 512 * qq];
    __syncthreads();
#pragma unroll
    for (int cc = 0; cc < 8; ++cc)
      acc += xsb[(size_t)(c0 + cc) * 1024 + s] * xrow[cc][sidx];
  }
  posl[dir * 65536 + b * 1024 + s] = acc * inv_src[b * 1024 + s] * sdinv[sidx] * TEMP_INV;
}

// ---------- neg GEMM + fused logsumexp (R5-proven staged) + folded finalize ----------
__global__ __launch_bounds__(256) void kneg(
    const float* __restrict__ xq, const float* __restrict__ xk,
    const float* __restrict__ x_invn,
    const float* __restrict__ adt, const float* __restrict__ posl,
    float* __restrict__ gsum, float* __restrict__ dsum, unsigned* __restrict__ cnt,
    const int* __restrict__ epoch, float* __restrict__ out) {
  int st = blockIdx.x, b = blockIdx.y, dir = blockIdx.z;
  const float* xsrc = dir == 0 ? xq : xk;
  const float* inv_src = x_invn + (dir ? 65536 : 0);
  const float* Bt = adt + dir * 8192;  // [128][64]

  __shared__ float As2[64][64];
  __shared__ float Bs2[128][64];
  __shared__ float red[16];

  int tid = threadIdx.x;
  int tx = tid & 15, ty = tid >> 4;
  int s0 = st * 64;

#pragma unroll
  for (int qq = 0; qq < 8; ++qq)
    reinterpret_cast<float4*>(Bs2)[tid + 256 * qq] =
        reinterpret_cast<const float4*>(Bt)[tid + 256 * qq];

  float acc[4][4];
#pragma unroll
  for (int i = 0; i < 4; ++i)
#pragma unroll
    for (int j = 0; j < 4; ++j) acc[i][j] = 0.f;

  int lm = tid & 63, lk = tid >> 6;
  float sinv = inv_src[b * 1024 + s0 + lm];
  const float* xb = xsrc + (size_t)b * 131072;

  for (int k0 = 0; k0 < 128; k0 += 64) {
#pragma unroll
    for (int r = 0; r < 16; ++r) {
      int kk = lk + 4 * r;
      As2[kk][lm] = xb[(k0 + kk) * 1024 + s0 + lm] * sinv;
    }
    __syncthreads();
#pragma unroll
    for (int kk = 0; kk < 64; ++kk) {
      float4 av = *reinterpret_cast<const float4*>(&As2[kk][ty * 4]);
      float4 bv = *reinterpret_cast<const float4*>(&Bs2[k0 + kk][tx * 4]);
      float a[4] = {av.x, av.y, av.z, av.w};
      float bb[4] = {bv.x, bv.y, bv.z, bv.w};
#pragma unroll
      for (int i = 0; i < 4; ++i)
#pragma unroll
        for (int j = 0; j < 4; ++j) acc[i][j] += a[i] * bb[j];
    }
    __syncthreads();
  }

  float lsum = 0.f;
#pragma unroll
  for (int i = 0; i < 4; ++i) {
    int s = s0 + ty * 4 + i;
    float pos = posl[dir * 65536 + b * 1024 + s];  // already *10
    float lg[4];
    float mloc = -INFINITY;
#pragma unroll
    for (int j = 0; j < 4; ++j) {
      int jg = tx * 4 + j;
      lg[j] = (jg == b) ? -INFINITY : acc[i][j] * TEMP_INV;
      mloc = fmaxf(mloc, lg[j]);
    }
#pragma unroll
    for (int mask = 1; mask <= 8; mask <<= 1) mloc = fmaxf(mloc, __shfl_xor(mloc, mask));
    float m = fmaxf(mloc, pos);
    float e = 0.f;
#pragma unroll
    for (int j = 0; j < 4; ++j) e += __expf(lg[j] - m);
#pragma unroll
    for (int mask = 1; mask <= 8; mask <<= 1) e += __shfl_xor(e, mask);
    if (tx == 0) lsum += m + __logf(e + __expf(pos - m)) - pos;
  }
  if (tx == 0) red[ty] = lsum;
  __syncthreads();
  if (tid == 0) {
    float v = 0.f;
#pragma unroll
    for (int r = 0; r < 16; ++r) v += red[r];
    atomicAdd(dsum, v);
    // folded finalize: last block of 2048 computes the output
    __threadfence();
    unsigned old = atomicAdd(cnt, 1u);
    if (old == 2047u) {
      __threadfence();
      float g = atomicAdd(gsum, 0.0f) / 128.0f;       // coherent device-scope read
      float dn = atomicAdd(dsum, 0.0f) / 131072.0f;   // (adds 0, returns current)
      out[0] = (epoch[0] > 0) ? (0.5f * g + 0.5f * dn) : g;  // WARMUP=0, COEFF=0.5
    }
  }
}

// ---------- launch ----------
extern "C" void kernel_launch(void* const* d_in, const int* in_sizes, int n_in,
                              void* d_out, int out_size, void* d_ws, size_t ws_size,
                              hipStream_t stream) {
  const float* ofq = (const float*)d_in[0];
  const float* agq = (const float*)d_in[1];
  const float* xq  = (const float*)d_in[2];
  const float* adq = (const float*)d_in[3];
  const float* ofk = (const float*)d_in[4];
  const float* agk = (const float*)d_in[5];
  const float* xk  = (const float*)d_in[6];
  const float* adk = (const float*)d_in[7];
  const int* epoch = (const int*)d_in[8];
  float* out = (float*)d_out;

  char* wsb = (char*)d_ws;
  __bf16* ofT = (__bf16*)wsb;                       // 64MB
  u64* best_row = (u64*)(wsb + 67108864);           // 512KB
  u64* best_col = best_row + 65536;                 // 512KB
  float* gsum = (float*)(best_col + 65536);
  float* dsum = gsum + 1;
  unsigned* cnt = (unsigned*)(dsum + 1);
  float* posl = (float*)(cnt + 2);                  // +pad: 16B-aligned
  float* x_invn  = posl + 131072;                   // 512KB
  float* of_invn = x_invn + 131072;                 // 512KB
  float* adt = of_invn + 131072;                    // 64KB

  // zero best arrays + gsum + dsum + cnt (+pad) in one memset
  hipMemsetAsync(best_row, 0, 65536ull * 8 * 2 + 16, stream);

  kcvt<<<4096, 256, 0, stream>>>(ofq, ofk, ofT, of_invn);

  dim3 gs(4, 4, 64);
  ksim<<<gs, 512, 0, stream>>>(ofT, of_invn, best_row, best_col);

  kpre2<<<640, 256, 0, stream>>>(xq, xk, x_invn, adq, adk, adt, agq, agk, gsum);

  dim3 gp(64, 2, 2);
  kpos<<<gp, 512, 0, stream>>>(xq, xk, x_invn, best_row, best_col, posl);

  dim3 gn(16, 64, 2);
  kneg<<<gn, 256, 0, stream>>>(xq, xk, x_invn, adt, posl, gsum, dsum, cnt, epoch, out);
}

// Round 9
// 385.912 us; speedup vs baseline: 1.0676x; 1.0676x over previous
//
#include <hip/hip_runtime.h>
#include <math.h>

// Problem constants: B=64/side (128 concat), d=256, C=128, S=1024, TEMP=0.1, COEFF=0.5
#define TEMP_INV 10.0f

typedef unsigned long long u64;
typedef __attribute__((ext_vector_type(8))) __bf16 bf16x8;
typedef __attribute__((ext_vector_type(4))) float f32x4;

// Monotone u32 key: fkey(a) > fkey(b) iff a > b (floats, no NaN).
__device__ inline unsigned fkey(float v) {
  unsigned u = __float_as_uint(v);
  return (u & 0x80000000u) ? ~u : (u | 0x80000000u);
}

// async global->LDS, 16B per lane (wave-uniform base + lane*16 ordering).
__device__ __forceinline__ void async_copy16(const void* gp, void* lp) {
  __builtin_amdgcn_global_load_lds(
      (__attribute__((address_space(1))) void*)(unsigned long long)gp,
      (__attribute__((address_space(3))) void*)(unsigned long long)lp,
      16, 0, 0);
}

// ---------- kcvt: transpose+bf16+norms [0,4096) + adt [4096,4160) + kglobal [4160,4224) ----------
// kcvt part is byte-identical to R8 (XCD co-mapping with ksim). The tiny
// adt/kglobal blocks (~130 KB reads) ride the grid tail — no L2 eviction risk.
__global__ __launch_bounds__(256) void kcvt(const float* __restrict__ ofq,
                                            const float* __restrict__ ofk,
                                            __bf16* __restrict__ ofT,
                                            float* __restrict__ of_invn,
                                            const float* __restrict__ adq,
                                            const float* __restrict__ adk,
                                            float* __restrict__ adt,
                                            const float* __restrict__ agq,
                                            const float* __restrict__ agk,
                                            float* __restrict__ gsum) {
  unsigned bx = blockIdx.x;
  int t = threadIdx.x;
  if (bx < 4096) {
    int xcd = bx & 7;
    unsigned idx = bx >> 3;       // 0..511 within XCD
    int j = idx >> 5;             // 0..15: pair (j>>1), side (j&1)
    int s0 = (idx & 31) * 32;
    int b = xcd + 8 * (j >> 1) + 64 * (j & 1);
    const float* src = (b < 64) ? (ofq + (size_t)b * 262144) : (ofk + (size_t)(b - 64) * 262144);
    __shared__ __bf16 T[8][32][36];  // per-iteration tiles, no reuse hazard
    __shared__ float R[8][32];
    int dd = t >> 5, ss = t & 31;
    int wr = t >> 3, wd = t & 7;
    float v[8][4];
    // phase 0: all 32 independent loads in flight
#pragma unroll
    for (int d0i = 0; d0i < 8; ++d0i)
#pragma unroll
      for (int it = 0; it < 4; ++it)
        v[d0i][it] = src[(size_t)(d0i * 32 + dd + 8 * it) * 1024 + s0 + ss];
    // ssq in the exact original order (d0 asc, it asc)
    float ssq = 0.f;
#pragma unroll
    for (int d0i = 0; d0i < 8; ++d0i)
#pragma unroll
      for (int it = 0; it < 4; ++it) ssq += v[d0i][it] * v[d0i][it];
    // phase 1: all transpose tiles + norm partials into LDS
#pragma unroll
    for (int d0i = 0; d0i < 8; ++d0i)
#pragma unroll
      for (int it = 0; it < 4; ++it) T[d0i][ss][dd + 8 * it] = (__bf16)v[d0i][it];
    R[dd][ss] = ssq;
    __syncthreads();  // the only barrier
    // phase 2: all output writes
    __bf16* out = ofT + (size_t)b * 262144 + (size_t)s0 * 256;
#pragma unroll
    for (int d0i = 0; d0i < 8; ++d0i)
      *(uint2*)(out + (size_t)wr * 256 + d0i * 32 + wd * 4) = *(const uint2*)(&T[d0i][wr][wd * 4]);
    if (t < 32) {
      float a = 0.f;
#pragma unroll
      for (int r = 0; r < 8; ++r) a += R[r][t];
      of_invn[b * 1024 + s0 + t] = 1.0f / fmaxf(sqrtf(a), 1e-12f);
    }
  } else if (bx < 4160) {
    // ---- adt transpose ----
    int i = (int)(bx - 4096) * 256 + t;  // 0..16383
    int dir = i >> 13, r = i & 8191;
    int jj = r >> 7, c = r & 127;
    const float* ad = dir == 0 ? adk : adq;
    adt[dir * 8192 + c * 64 + jj] = ad[jj * 128 + c];
  } else {
    // ---- kglobal: 2 rows i per block (t<128 -> i0, t>=128 -> i0+1) ----
    __shared__ float logits[2][128];
    __shared__ float rinv[128];
    int ii = t >> 7, jl = t & 127;
    int i = (int)(bx - 4160) * 2 + ii;
    const float* rowi = (i < 64) ? (agq + i * 128) : (agk + (i - 64) * 128);
    const float* rowj = (jl < 64) ? (agq + jl * 128) : (agk + (jl - 64) * 128);
    float dot = 0.f, nj = 0.f;
#pragma unroll 8
    for (int c = 0; c < 128; ++c) { float a = rowi[c], bb = rowj[c]; dot += a * bb; nj += bb * bb; }
    if (ii == 0) rinv[jl] = 1.0f / fmaxf(sqrtf(nj), 1e-12f);
    __syncthreads();
    logits[ii][jl] = dot * rinv[i] * rinv[jl] * TEMP_INV;
    __syncthreads();
    if (jl == 0) {
      int pos = (i + 64) & 127;
      float m = -INFINITY;
      for (int tt = 0; tt < 128; ++tt) if (tt != i) m = fmaxf(m, logits[ii][tt]);
      float e = 0.f;
      for (int tt = 0; tt < 128; ++tt) if (tt != i) e += __expf(logits[ii][tt] - m);
      atomicAdd(gsum, m + __logf(e) - logits[ii][pos]);
    }
  }
}

// ---------- MFMA sim GEMM + dual argmax (R8-proven: 91.5 us, FETCH 33 MB) ----------
// 256x256 tile, 8 waves (2M x 4N), BK=64, double-buffered, G4 XOR-swizzled LDS,
// b<->XCD affinity, reverse-b freshness order vs kcvt.
__global__ __launch_bounds__(512, 2) void ksim(
    const __bf16* __restrict__ ofT, const float* __restrict__ of_invn,
    u64* __restrict__ best_row, u64* __restrict__ best_col) {
  // hardware linear block id -> (xcd, slot); b % 8 == xcd; 1024 = 8 XCD x 128
  unsigned h = blockIdx.x + (blockIdx.y << 2) + (blockIdx.z << 4);
  int xcd = h & 7;
  unsigned slot = h >> 3;                       // 0..127 within XCD
  int b = xcd + 8 * (7 - (int)(slot >> 4));     // reverse freshness order
  int tile = slot & 15;
  int s0 = (tile & 3) * 256, t0 = (tile >> 2) * 256;

  const __bf16* Ag = ofT + (size_t)b * 262144;        // q rows [1024][256]
  const __bf16* Bg = ofT + (size_t)(b + 64) * 262144; // k rows
  __shared__ __bf16 As[2][16384];  // 64 KiB
  __shared__ __bf16 Bs[2][16384];  // 64 KiB  (total 128 KiB)

  int t = threadIdx.x;
  int lane = t & 63, w = t >> 6;
  int lc = lane & 15, q = lane >> 4;
  int wm = w >> 2, wn = w & 3;  // 2 x 4 wave grid; wave owns 128(M) x 64(N)

  f32x4 acc[8][4];
#pragma unroll
  for (int i = 0; i < 8; ++i)
#pragma unroll
    for (int j = 0; j < 4; ++j) acc[i][j] = (f32x4)(0.f);

  // fragment LDS offsets (bf16 units), kk=0; kk=1 reads offset ^ 32
  int aoff[8], boff[4];
#pragma unroll
  for (int i = 0; i < 8; ++i) {
    int mr = wm * 128 + i * 16 + lc;
    aoff[i] = mr * 64 + ((q ^ (mr & 7)) << 3);
  }
#pragma unroll
  for (int j = 0; j < 4; ++j) {
    int nc = wn * 64 + j * 16 + lc;
    boff[j] = nc * 64 + ((q ^ (nc & 7)) << 3);
  }

  // staging: thread t, chunk c: row m = c*64 + (t>>3), phys slot g = t&7,
  // logical group lg = g ^ (m&7) = g ^ ((t>>3)&7)  (c*64 is 0 mod 8)
  int ms = t >> 3, gphys = t & 7;
  int lg = gphys ^ (ms & 7);
  size_t aSrc = (size_t)(s0 + ms) * 256 + lg * 8;
  size_t bSrc = (size_t)(t0 + ms) * 256 + lg * 8;

  auto STAGE = [&](int bufn, int k0) {
    char* aL = (char*)&As[bufn][0] + t * 16;
    char* bL = (char*)&Bs[bufn][0] + t * 16;
#pragma unroll
    for (int c = 0; c < 4; ++c) {
      async_copy16(Ag + aSrc + (size_t)c * 16384 + k0, aL + c * 8192);
      async_copy16(Bg + bSrc + (size_t)c * 16384 + k0, bL + c * 8192);
    }
  };

  // prologue: stage k0=0 into buf 0
  STAGE(0, 0);
  __syncthreads();

  for (int it = 0; it < 4; ++it) {
    int buf = it & 1;
    if (it < 3) STAGE(buf ^ 1, (it + 1) * 64);
#pragma unroll
    for (int kk = 0; kk < 2; ++kk) {
      int kx = kk << 5;  // ^32 toggles phys k-group bit 2
      bf16x8 af[8], bfr[4];
#pragma unroll
      for (int i = 0; i < 8; ++i) af[i] = *(const bf16x8*)(&As[buf][0] + (aoff[i] ^ kx));
#pragma unroll
      for (int j = 0; j < 4; ++j) bfr[j] = *(const bf16x8*)(&Bs[buf][0] + (boff[j] ^ kx));
      __builtin_amdgcn_s_setprio(1);
#pragma unroll
      for (int i = 0; i < 8; ++i)
#pragma unroll
        for (int j = 0; j < 4; ++j)
          acc[i][j] = __builtin_amdgcn_mfma_f32_16x16x32_bf16(af[i], bfr[j], acc[i][j], 0, 0, 0);
      __builtin_amdgcn_s_setprio(0);
    }
    __syncthreads();  // readers done with buf + drains prefetch vmcnt
  }

  // ---- epilogue (f32 domain). C/D layout: col=lane&15, row=(lane>>4)*4+reg ----
  float sk[4];
#pragma unroll
  for (int j = 0; j < 4; ++j) sk[j] = of_invn[65536 + b * 1024 + t0 + wn * 64 + j * 16 + lc];
  float sq[32];
#pragma unroll
  for (int i = 0; i < 8; ++i)
#pragma unroll
    for (int e = 0; e < 4; ++e)
      sq[i * 4 + e] = of_invn[b * 1024 + s0 + wm * 128 + i * 16 + q * 4 + e];

  u64* browb = best_row + (size_t)b * 1024 + s0;
  u64* bcolb = best_col + (size_t)b * 1024 + t0;

  // row direction: argmax over t for fixed s (scale by sik only; siq>0 dropped)
#pragma unroll
  for (int i = 0; i < 8; ++i) {
#pragma unroll
    for (int e = 0; e < 4; ++e) {
      float v[4];
#pragma unroll
      for (int j = 0; j < 4; ++j) v[j] = acc[i][j][e] * sk[j];
      float vb = fmaxf(fmaxf(v[0], v[1]), fmaxf(v[2], v[3]));
#pragma unroll
      for (int mask = 1; mask <= 8; mask <<= 1) vb = fmaxf(vb, __shfl_xor(vb, mask));
      unsigned ib = 0xFFFFFFFFu;
#pragma unroll
      for (int j = 0; j < 4; ++j) {
        unsigned cand = (v[j] == vb) ? (unsigned)(t0 + wn * 64 + j * 16 + lc) : 0xFFFFFFFFu;
        ib = min(ib, cand);
      }
#pragma unroll
      for (int mask = 1; mask <= 8; mask <<= 1) ib = min(ib, __shfl_xor(ib, mask));
      if (lc == 0)
        atomicMax(browb + wm * 128 + i * 16 + q * 4 + e,
                  ((u64)fkey(vb) << 32) | (u64)(0xFFFFFFFFu - ib));
    }
  }

  // col direction: argmax over s for fixed t (scale by siq only)
#pragma unroll
  for (int j = 0; j < 4; ++j) {
    float cb = -INFINITY;
#pragma unroll
    for (int i = 0; i < 8; ++i)
#pragma unroll
      for (int e = 0; e < 4; ++e) cb = fmaxf(cb, acc[i][j][e] * sq[i * 4 + e]);
    cb = fmaxf(cb, __shfl_xor(cb, 16));
    cb = fmaxf(cb, __shfl_xor(cb, 32));
    unsigned ib = 0xFFFFFFFFu;
#pragma unroll
    for (int i = 0; i < 8; ++i)
#pragma unroll
      for (int e = 0; e < 4; ++e) {
        float m2 = acc[i][j][e] * sq[i * 4 + e];  // bitwise-identical recompute
        unsigned cand = (m2 == cb) ? (unsigned)(s0 + wm * 128 + i * 16 + q * 4 + e) : 0xFFFFFFFFu;
        ib = min(ib, cand);
      }
    ib = min(ib, __shfl_xor(ib, 16));
    ib = min(ib, __shfl_xor(ib, 32));
    if (lane < 16)
      atomicMax(bcolb + wn * 64 + j * 16 + lane,
                ((u64)fkey(cb) << 32) | (u64)(0xFFFFFFFFu - ib));
  }
}

// ---------- pos logits + fused x_invn production ----------
// R9: R5-proven 1024-thread structure. x_invn is computed HERE (not a prior
// pass): ssq_s over the thread's own xsrc column and ssq_d over column sidx of
// the staged xrow, both in the same c-ascending order as the old kprep pass =>
// bit-identical invs/invd => posl and kneg's sinv unchanged. Deletes the
// 128 MB x_invn pre-pass entirely.
__global__ __launch_bounds__(1024) void kpos(
    const float* __restrict__ xq, const float* __restrict__ xk,
    float* __restrict__ x_invn,
    const u64* __restrict__ best_row, const u64* __restrict__ best_col,
    float* __restrict__ posl) {
  int b = blockIdx.x, dir = blockIdx.y;
  const float* xsrc = dir == 0 ? xq : xk;
  const float* xdst = dir == 0 ? xk : xq;
  const u64* best = dir == 0 ? best_row : best_col;

  __shared__ float xrow[8][1024];  // 32KB
  int t = threadIdx.x;  // = s
  u64 p = best[(size_t)b * 1024 + t];
  int sidx = (int)(0xFFFFFFFFu - (unsigned)(p & 0xFFFFFFFFull));
  const float* xsb = xsrc + (size_t)b * 131072;
  const float* xdb = xdst + (size_t)b * 131072;
  float acc = 0.f, ssq_s = 0.f, ssq_d = 0.f;
  for (int c0 = 0; c0 < 128; c0 += 8) {
    __syncthreads();
#pragma unroll
    for (int qq = 0; qq < 2; ++qq)
      ((float4*)xrow)[t + 1024 * qq] = ((const float4*)(xdb + (size_t)c0 * 1024))[t + 1024 * qq];
    __syncthreads();
#pragma unroll
    for (int cc = 0; cc < 8; ++cc) {
      float a_ = xsb[(size_t)(c0 + cc) * 1024 + t];
      float d_ = xrow[cc][sidx];
      acc += a_ * d_;
      ssq_s += a_ * a_;
      ssq_d += d_ * d_;
    }
  }
  float invs = 1.0f / fmaxf(sqrtf(ssq_s), 1e-12f);
  float invd = 1.0f / fmaxf(sqrtf(ssq_d), 1e-12f);
  posl[dir * 65536 + b * 1024 + t] = acc * invs * invd * TEMP_INV;
  x_invn[(dir ? 65536 : 0) + b * 1024 + t] = invs;  // consumed by kneg
}

// ---------- neg GEMM + fused logsumexp (R5-proven staged version) ----------
__global__ __launch_bounds__(256) void kneg(
    const float* __restrict__ xq, const float* __restrict__ xk,
    const float* __restrict__ x_invn,
    const float* __restrict__ adt, const float* __restrict__ posl,
    float* __restrict__ dsum) {
  int st = blockIdx.x, b = blockIdx.y, dir = blockIdx.z;
  const float* xsrc = dir == 0 ? xq : xk;
  const float* inv_src = x_invn + (dir ? 65536 : 0);
  const float* Bt = adt + dir * 8192;  // [128][64]

  __shared__ float As2[64][64];
  __shared__ float Bs2[128][64];
  __shared__ float red[16];

  int tid = threadIdx.x;
  int tx = tid & 15, ty = tid >> 4;
  int s0 = st * 64;

#pragma unroll
  for (int qq = 0; qq < 8; ++qq)
    reinterpret_cast<float4*>(Bs2)[tid + 256 * qq] =
        reinterpret_cast<const float4*>(Bt)[tid + 256 * qq];

  float acc[4][4];
#pragma unroll
  for (int i = 0; i < 4; ++i)
#pragma unroll
    for (int j = 0; j < 4; ++j) acc[i][j] = 0.f;

  int lm = tid & 63, lk = tid >> 6;
  float sinv = inv_src[b * 1024 + s0 + lm];
  const float* xb = xsrc + (size_t)b * 131072;

  for (int k0 = 0; k0 < 128; k0 += 64) {
#pragma unroll
    for (int r = 0; r < 16; ++r) {
      int kk = lk + 4 * r;
      As2[kk][lm] = xb[(k0 + kk) * 1024 + s0 + lm] * sinv;
    }
    __syncthreads();
#pragma unroll
    for (int kk = 0; kk < 64; ++kk) {
      float4 av = *reinterpret_cast<const float4*>(&As2[kk][ty * 4]);
      float4 bv = *reinterpret_cast<const float4*>(&Bs2[k0 + kk][tx * 4]);
      float a[4] = {av.x, av.y, av.z, av.w};
      float bb[4] = {bv.x, bv.y, bv.z, bv.w};
#pragma unroll
      for (int i = 0; i < 4; ++i)
#pragma unroll
        for (int j = 0; j < 4; ++j) acc[i][j] += a[i] * bb[j];
    }
    __syncthreads();
  }

  float lsum = 0.f;
#pragma unroll
  for (int i = 0; i < 4; ++i) {
    int s = s0 + ty * 4 + i;
    float pos = posl[dir * 65536 + b * 1024 + s];  // already *10
    float lg[4];
    float mloc = -INFINITY;
#pragma unroll
    for (int j = 0; j < 4; ++j) {
      int jg = tx * 4 + j;
      lg[j] = (jg == b) ? -INFINITY : acc[i][j] * TEMP_INV;
      mloc = fmaxf(mloc, lg[j]);
    }
#pragma unroll
    for (int mask = 1; mask <= 8; mask <<= 1) mloc = fmaxf(mloc, __shfl_xor(mloc, mask));
    float m = fmaxf(mloc, pos);
    float e = 0.f;
#pragma unroll
    for (int j = 0; j < 4; ++j) e += __expf(lg[j] - m);
#pragma unroll
    for (int mask = 1; mask <= 8; mask <<= 1) e += __shfl_xor(e, mask);
    if (tx == 0) lsum += m + __logf(e + __expf(pos - m)) - pos;
  }
  if (tx == 0) red[ty] = lsum;
  __syncthreads();
  if (tid == 0) {
    float v = 0.f;
#pragma unroll
    for (int r = 0; r < 16; ++r) v += red[r];
    atomicAdd(dsum, v);
  }
}

__global__ void kfinal(const float* __restrict__ gsum, const float* __restrict__ dsum,
                       const int* __restrict__ epoch, float* __restrict__ out) {
  if (threadIdx.x == 0) {
    float g = gsum[0] / 128.0f;
    float dn = dsum[0] / 131072.0f;
    out[0] = (epoch[0] > 0) ? (0.5f * g + 0.5f * dn) : g;  // WARMUP=0, COEFF=0.5
  }
}

// ---------- launch ----------
extern "C" void kernel_launch(void* const* d_in, const int* in_sizes, int n_in,
                              void* d_out, int out_size, void* d_ws, size_t ws_size,
                              hipStream_t stream) {
  const float* ofq = (const float*)d_in[0];
  const float* agq = (const float*)d_in[1];
  const float* xq  = (const float*)d_in[2];
  const float* adq = (const float*)d_in[3];
  const float* ofk = (const float*)d_in[4];
  const float* agk = (const float*)d_in[5];
  const float* xk  = (const float*)d_in[6];
  const float* adk = (const float*)d_in[7];
  const int* epoch = (const int*)d_in[8];
  float* out = (float*)d_out;

  char* wsb = (char*)d_ws;
  __bf16* ofT = (__bf16*)wsb;                       // 64MB
  u64* best_row = (u64*)(wsb + 67108864);           // 512KB
  u64* best_col = best_row + 65536;                 // 512KB
  float* gsum = (float*)(best_col + 65536);
  float* dsum = gsum + 1;
  float* posl = dsum + 1;                           // 512KB
  float* x_invn  = posl + 131072;                   // 512KB (written by kpos)
  float* of_invn = x_invn + 131072;                 // 512KB
  float* adt = of_invn + 131072;                    // 64KB

  // zero best arrays (packed 0 < any real key) + gsum + dsum in one memset
  hipMemsetAsync(best_row, 0, 65536ull * 8 * 2 + 8, stream);

  kcvt<<<4224, 256, 0, stream>>>(ofq, ofk, ofT, of_invn, adq, adk, adt, agq, agk, gsum);

  dim3 gs(4, 4, 64);
  ksim<<<gs, 512, 0, stream>>>(ofT, of_invn, best_row, best_col);

  dim3 gp(64, 2);
  kpos<<<gp, 1024, 0, stream>>>(xq, xk, x_invn, best_row, best_col, posl);

  dim3 gn(16, 64, 2);
  kneg<<<gn, 256, 0, stream>>>(xq, xk, x_invn, adt, posl, dsum);

  kfinal<<<1, 1, 0, stream>>>(gsum, dsum, epoch, out);
}

// Round 10
// 375.664 us; speedup vs baseline: 1.0967x; 1.0273x over previous
//
#include <hip/hip_runtime.h>
#include <math.h>

// Problem constants: B=64/side (128 concat), d=256, C=128, S=1024, TEMP=0.1, COEFF=0.5
#define TEMP_INV 10.0f

typedef unsigned long long u64;
typedef __attribute__((ext_vector_type(8))) __bf16 bf16x8;
typedef __attribute__((ext_vector_type(4))) float f32x4;

// Monotone u32 key: fkey(a) > fkey(b) iff a > b (floats, no NaN).
__device__ inline unsigned fkey(float v) {
  unsigned u = __float_as_uint(v);
  return (u & 0x80000000u) ? ~u : (u | 0x80000000u);
}

// async global->LDS, 16B per lane (wave-uniform base + lane*16 ordering).
__device__ __forceinline__ void async_copy16(const void* gp, void* lp) {
  __builtin_amdgcn_global_load_lds(
      (__attribute__((address_space(1))) void*)(unsigned long long)gp,
      (__attribute__((address_space(3))) void*)(unsigned long long)lp,
      16, 0, 0);
}

// ---------- kcvt: transpose+bf16+norms [0,4096) + adt [4096,4160) + kglobal [4160,4224) ----------
// R10: G13 vectorization — 8x float4 loads/thread (16B/lane) into LDS f32
// F[256][33], then ssq re-read per-column in the ORIGINAL (d0i asc, it asc)
// order (bit-identical of_invn) and 16B uint4 stores (per-element (__bf16)
// cast unchanged => bit-identical ofT). XCD co-mapping with ksim preserved.
__global__ __launch_bounds__(256) void kcvt(const float* __restrict__ ofq,
                                            const float* __restrict__ ofk,
                                            __bf16* __restrict__ ofT,
                                            float* __restrict__ of_invn,
                                            const float* __restrict__ adq,
                                            const float* __restrict__ adk,
                                            float* __restrict__ adt,
                                            const float* __restrict__ agq,
                                            const float* __restrict__ agk,
                                            float* __restrict__ gsum) {
  unsigned bx = blockIdx.x;
  int t = threadIdx.x;
  if (bx < 4096) {
    int xcd = bx & 7;
    unsigned idx = bx >> 3;       // 0..511 within XCD
    int j = idx >> 5;             // 0..15: pair (j>>1), side (j&1)
    int s0 = (idx & 31) * 32;
    int b = xcd + 8 * (j >> 1) + 64 * (j & 1);
    const float* src = (b < 64) ? (ofq + (size_t)b * 262144) : (ofk + (size_t)(b - 64) * 262144);
    __shared__ float F[256][33];  // 33792 B, +1 pad: <=2-way banks everywhere
    __shared__ float R[8][32];
    // phase A: 8 x float4 loads (16B/lane, coalesced 1KB/wave-instr)
    int dr = t >> 3, sq = (t & 7) * 4;
    float4 f4[8];
#pragma unroll
    for (int d0i = 0; d0i < 8; ++d0i)
      f4[d0i] = *(const float4*)&src[(size_t)(d0i * 32 + dr) * 1024 + s0 + sq];
#pragma unroll
    for (int d0i = 0; d0i < 8; ++d0i) {
      F[d0i * 32 + dr][sq]     = f4[d0i].x;
      F[d0i * 32 + dr][sq + 1] = f4[d0i].y;
      F[d0i * 32 + dr][sq + 2] = f4[d0i].z;
      F[d0i * 32 + dr][sq + 3] = f4[d0i].w;
    }
    __syncthreads();
    // ssq per column, exact original order (dd = t>>5, ss = t&31)
    int dd = t >> 5, ss = t & 31;
    float ssq = 0.f;
#pragma unroll
    for (int d0i = 0; d0i < 8; ++d0i)
#pragma unroll
      for (int it = 0; it < 4; ++it) {
        float val = F[d0i * 32 + dd + 8 * it][ss];
        ssq += val * val;
      }
    R[dd][ss] = ssq;
    // stores: 4 granules of 8 bf16 (16B) per thread, contiguous per wave
    __bf16* out = ofT + (size_t)b * 262144 + (size_t)s0 * 256;
#pragma unroll
    for (int gi = 0; gi < 4; ++gi) {
      int G = t + gi * 256;
      int row = G >> 5, c16 = G & 31;
      unsigned u[8];
#pragma unroll
      for (int jj = 0; jj < 8; ++jj) {
        __bf16 hv = (__bf16)F[c16 * 8 + jj][row];
        u[jj] = *(unsigned short*)&hv;
      }
      uint4 pack;
      pack.x = u[0] | (u[1] << 16);
      pack.y = u[2] | (u[3] << 16);
      pack.z = u[4] | (u[5] << 16);
      pack.w = u[6] | (u[7] << 16);
      *(uint4*)(out + (size_t)row * 256 + c16 * 8) = pack;
    }
    __syncthreads();
    if (t < 32) {
      float a = 0.f;
#pragma unroll
      for (int r = 0; r < 8; ++r) a += R[r][t];
      of_invn[b * 1024 + s0 + t] = 1.0f / fmaxf(sqrtf(a), 1e-12f);
    }
  } else if (bx < 4160) {
    // ---- adt transpose ----
    int i = (int)(bx - 4096) * 256 + t;  // 0..16383
    int dir = i >> 13, r = i & 8191;
    int jj = r >> 7, c = r & 127;
    const float* ad = dir == 0 ? adk : adq;
    adt[dir * 8192 + c * 64 + jj] = ad[jj * 128 + c];
  } else {
    // ---- kglobal: 2 rows i per block (t<128 -> i0, t>=128 -> i0+1) ----
    __shared__ float logits[2][128];
    __shared__ float rinv[128];
    int ii = t >> 7, jl = t & 127;
    int i = (int)(bx - 4160) * 2 + ii;
    const float* rowi = (i < 64) ? (agq + i * 128) : (agk + (i - 64) * 128);
    const float* rowj = (jl < 64) ? (agq + jl * 128) : (agk + (jl - 64) * 128);
    float dot = 0.f, nj = 0.f;
#pragma unroll 8
    for (int c = 0; c < 128; ++c) { float a = rowi[c], bb = rowj[c]; dot += a * bb; nj += bb * bb; }
    if (ii == 0) rinv[jl] = 1.0f / fmaxf(sqrtf(nj), 1e-12f);
    __syncthreads();
    logits[ii][jl] = dot * rinv[i] * rinv[jl] * TEMP_INV;
    __syncthreads();
    if (jl == 0) {
      int pos = (i + 64) & 127;
      float m = -INFINITY;
      for (int tt = 0; tt < 128; ++tt) if (tt != i) m = fmaxf(m, logits[ii][tt]);
      float e = 0.f;
      for (int tt = 0; tt < 128; ++tt) if (tt != i) e += __expf(logits[ii][tt] - m);
      atomicAdd(gsum, m + __logf(e) - logits[ii][pos]);
    }
  }
}

// ---------- MFMA sim GEMM + dual argmax (R8-proven body: 90.3 us, FETCH 33 MB) ----------
// R10: launched as TWO z=32 dispatches (hoff 0 / 512) so non-ksim kernels
// surface in the rocprof top-5. Block->(b,tile) mapping byte-equivalent to
// the single-launch version.
__global__ __launch_bounds__(512, 2) void ksim(
    const __bf16* __restrict__ ofT, const float* __restrict__ of_invn,
    u64* __restrict__ best_row, u64* __restrict__ best_col, int hoff) {
  // hardware linear block id -> (xcd, slot); b % 8 == xcd; 1024 = 8 XCD x 128
  unsigned h = blockIdx.x + (blockIdx.y << 2) + (blockIdx.z << 4) + (unsigned)hoff;
  int xcd = h & 7;
  unsigned slot = h >> 3;                       // 0..127 within XCD
  int b = xcd + 8 * (7 - (int)(slot >> 4));     // reverse freshness order
  int tile = slot & 15;
  int s0 = (tile & 3) * 256, t0 = (tile >> 2) * 256;

  const __bf16* Ag = ofT + (size_t)b * 262144;        // q rows [1024][256]
  const __bf16* Bg = ofT + (size_t)(b + 64) * 262144; // k rows
  __shared__ __bf16 As[2][16384];  // 64 KiB
  __shared__ __bf16 Bs[2][16384];  // 64 KiB  (total 128 KiB)

  int t = threadIdx.x;
  int lane = t & 63, w = t >> 6;
  int lc = lane & 15, q = lane >> 4;
  int wm = w >> 2, wn = w & 3;  // 2 x 4 wave grid; wave owns 128(M) x 64(N)

  f32x4 acc[8][4];
#pragma unroll
  for (int i = 0; i < 8; ++i)
#pragma unroll
    for (int j = 0; j < 4; ++j) acc[i][j] = (f32x4)(0.f);

  // fragment LDS offsets (bf16 units), kk=0; kk=1 reads offset ^ 32
  int aoff[8], boff[4];
#pragma unroll
  for (int i = 0; i < 8; ++i) {
    int mr = wm * 128 + i * 16 + lc;
    aoff[i] = mr * 64 + ((q ^ (mr & 7)) << 3);
  }
#pragma unroll
  for (int j = 0; j < 4; ++j) {
    int nc = wn * 64 + j * 16 + lc;
    boff[j] = nc * 64 + ((q ^ (nc & 7)) << 3);
  }

  // staging: thread t, chunk c: row m = c*64 + (t>>3), phys slot g = t&7,
  // logical group lg = g ^ (m&7) = g ^ ((t>>3)&7)  (c*64 is 0 mod 8)
  int ms = t >> 3, gphys = t & 7;
  int lg = gphys ^ (ms & 7);
  size_t aSrc = (size_t)(s0 + ms) * 256 + lg * 8;
  size_t bSrc = (size_t)(t0 + ms) * 256 + lg * 8;

  auto STAGE = [&](int bufn, int k0) {
    char* aL = (char*)&As[bufn][0] + t * 16;
    char* bL = (char*)&Bs[bufn][0] + t * 16;
#pragma unroll
    for (int c = 0; c < 4; ++c) {
      async_copy16(Ag + aSrc + (size_t)c * 16384 + k0, aL + c * 8192);
      async_copy16(Bg + bSrc + (size_t)c * 16384 + k0, bL + c * 8192);
    }
  };

  // prologue: stage k0=0 into buf 0
  STAGE(0, 0);
  __syncthreads();

  for (int it = 0; it < 4; ++it) {
    int buf = it & 1;
    if (it < 3) STAGE(buf ^ 1, (it + 1) * 64);
#pragma unroll
    for (int kk = 0; kk < 2; ++kk) {
      int kx = kk << 5;  // ^32 toggles phys k-group bit 2
      bf16x8 af[8], bfr[4];
#pragma unroll
      for (int i = 0; i < 8; ++i) af[i] = *(const bf16x8*)(&As[buf][0] + (aoff[i] ^ kx));
#pragma unroll
      for (int j = 0; j < 4; ++j) bfr[j] = *(const bf16x8*)(&Bs[buf][0] + (boff[j] ^ kx));
      __builtin_amdgcn_s_setprio(1);
#pragma unroll
      for (int i = 0; i < 8; ++i)
#pragma unroll
        for (int j = 0; j < 4; ++j)
          acc[i][j] = __builtin_amdgcn_mfma_f32_16x16x32_bf16(af[i], bfr[j], acc[i][j], 0, 0, 0);
      __builtin_amdgcn_s_setprio(0);
    }
    __syncthreads();  // readers done with buf + drains prefetch vmcnt
  }

  // ---- epilogue (f32 domain). C/D layout: col=lane&15, row=(lane>>4)*4+reg ----
  float sk[4];
#pragma unroll
  for (int j = 0; j < 4; ++j) sk[j] = of_invn[65536 + b * 1024 + t0 + wn * 64 + j * 16 + lc];
  float sq[32];
#pragma unroll
  for (int i = 0; i < 8; ++i)
#pragma unroll
    for (int e = 0; e < 4; ++e)
      sq[i * 4 + e] = of_invn[b * 1024 + s0 + wm * 128 + i * 16 + q * 4 + e];

  u64* browb = best_row + (size_t)b * 1024 + s0;
  u64* bcolb = best_col + (size_t)b * 1024 + t0;

  // row direction: argmax over t for fixed s (scale by sik only; siq>0 dropped)
#pragma unroll
  for (int i = 0; i < 8; ++i) {
#pragma unroll
    for (int e = 0; e < 4; ++e) {
      float v[4];
#pragma unroll
      for (int j = 0; j < 4; ++j) v[j] = acc[i][j][e] * sk[j];
      float vb = fmaxf(fmaxf(v[0], v[1]), fmaxf(v[2], v[3]));
#pragma unroll
      for (int mask = 1; mask <= 8; mask <<= 1) vb = fmaxf(vb, __shfl_xor(vb, mask));
      unsigned ib = 0xFFFFFFFFu;
#pragma unroll
      for (int j = 0; j < 4; ++j) {
        unsigned cand = (v[j] == vb) ? (unsigned)(t0 + wn * 64 + j * 16 + lc) : 0xFFFFFFFFu;
        ib = min(ib, cand);
      }
#pragma unroll
      for (int mask = 1; mask <= 8; mask <<= 1) ib = min(ib, __shfl_xor(ib, mask));
      if (lc == 0)
        atomicMax(browb + wm * 128 + i * 16 + q * 4 + e,
                  ((u64)fkey(vb) << 32) | (u64)(0xFFFFFFFFu - ib));
    }
  }

  // col direction: argmax over s for fixed t (scale by siq only)
#pragma unroll
  for (int j = 0; j < 4; ++j) {
    float cb = -INFINITY;
#pragma unroll
    for (int i = 0; i < 8; ++i)
#pragma unroll
      for (int e = 0; e < 4; ++e) cb = fmaxf(cb, acc[i][j][e] * sq[i * 4 + e]);
    cb = fmaxf(cb, __shfl_xor(cb, 16));
    cb = fmaxf(cb, __shfl_xor(cb, 32));
    unsigned ib = 0xFFFFFFFFu;
#pragma unroll
    for (int i = 0; i < 8; ++i)
#pragma unroll
      for (int e = 0; e < 4; ++e) {
        float m2 = acc[i][j][e] * sq[i * 4 + e];  // bitwise-identical recompute
        unsigned cand = (m2 == cb) ? (unsigned)(s0 + wm * 128 + i * 16 + q * 4 + e) : 0xFFFFFFFFu;
        ib = min(ib, cand);
      }
    ib = min(ib, __shfl_xor(ib, 16));
    ib = min(ib, __shfl_xor(ib, 32));
    if (lane < 16)
      atomicMax(bcolb + wn * 64 + j * 16 + lane,
                ((u64)fkey(cb) << 32) | (u64)(0xFFFFFFFFu - ib));
  }
}

// ---------- pos logits + fused x_invn production (R9-proven) ----------
__global__ __launch_bounds__(1024) void kpos(
    const float* __restrict__ xq, const float* __restrict__ xk,
    float* __restrict__ x_invn,
    const u64* __restrict__ best_row, const u64* __restrict__ best_col,
    float* __restrict__ posl) {
  int b = blockIdx.x, dir = blockIdx.y;
  const float* xsrc = dir == 0 ? xq : xk;
  const float* xdst = dir == 0 ? xk : xq;
  const u64* best = dir == 0 ? best_row : best_col;

  __shared__ float xrow[8][1024];  // 32KB
  int t = threadIdx.x;  // = s
  u64 p = best[(size_t)b * 1024 + t];
  int sidx = (int)(0xFFFFFFFFu - (unsigned)(p & 0xFFFFFFFFull));
  const float* xsb = xsrc + (size_t)b * 131072;
  const float* xdb = xdst + (size_t)b * 131072;
  float acc = 0.f, ssq_s = 0.f, ssq_d = 0.f;
  for (int c0 = 0; c0 < 128; c0 += 8) {
    __syncthreads();
#pragma unroll
    for (int qq = 0; qq < 2; ++qq)
      ((float4*)xrow)[t + 1024 * qq] = ((const float4*)(xdb + (size_t)c0 * 1024))[t + 1024 * qq];
    __syncthreads();
#pragma unroll
    for (int cc = 0; cc < 8; ++cc) {
      float a_ = xsb[(size_t)(c0 + cc) * 1024 + t];
      float d_ = xrow[cc][sidx];
      acc += a_ * d_;
      ssq_s += a_ * a_;
      ssq_d += d_ * d_;
    }
  }
  float invs = 1.0f / fmaxf(sqrtf(ssq_s), 1e-12f);
  float invd = 1.0f / fmaxf(sqrtf(ssq_d), 1e-12f);
  posl[dir * 65536 + b * 1024 + t] = acc * invs * invd * TEMP_INV;
  x_invn[(dir ? 65536 : 0) + b * 1024 + t] = invs;  // consumed by kneg
}

// ---------- neg GEMM + fused logsumexp (R5-proven staged version) ----------
__global__ __launch_bounds__(256) void kneg(
    const float* __restrict__ xq, const float* __restrict__ xk,
    const float* __restrict__ x_invn,
    const float* __restrict__ adt, const float* __restrict__ posl,
    float* __restrict__ dsum) {
  int st = blockIdx.x, b = blockIdx.y, dir = blockIdx.z;
  const float* xsrc = dir == 0 ? xq : xk;
  const float* inv_src = x_invn + (dir ? 65536 : 0);
  const float* Bt = adt + dir * 8192;  // [128][64]

  __shared__ float As2[64][64];
  __shared__ float Bs2[128][64];
  __shared__ float red[16];

  int tid = threadIdx.x;
  int tx = tid & 15, ty = tid >> 4;
  int s0 = st * 64;

#pragma unroll
  for (int qq = 0; qq < 8; ++qq)
    reinterpret_cast<float4*>(Bs2)[tid + 256 * qq] =
        reinterpret_cast<const float4*>(Bt)[tid + 256 * qq];

  float acc[4][4];
#pragma unroll
  for (int i = 0; i < 4; ++i)
#pragma unroll
    for (int j = 0; j < 4; ++j) acc[i][j] = 0.f;

  int lm = tid & 63, lk = tid >> 6;
  float sinv = inv_src[b * 1024 + s0 + lm];
  const float* xb = xsrc + (size_t)b * 131072;

  for (int k0 = 0; k0 < 128; k0 += 64) {
#pragma unroll
    for (int r = 0; r < 16; ++r) {
      int kk = lk + 4 * r;
      As2[kk][lm] = xb[(k0 + kk) * 1024 + s0 + lm] * sinv;
    }
    __syncthreads();
#pragma unroll
    for (int kk = 0; kk < 64; ++kk) {
      float4 av = *reinterpret_cast<const float4*>(&As2[kk][ty * 4]);
      float4 bv = *reinterpret_cast<const float4*>(&Bs2[k0 + kk][tx * 4]);
      float a[4] = {av.x, av.y, av.z, av.w};
      float bb[4] = {bv.x, bv.y, bv.z, bv.w};
#pragma unroll
      for (int i = 0; i < 4; ++i)
#pragma unroll
        for (int j = 0; j < 4; ++j) acc[i][j] += a[i] * bb[j];
    }
    __syncthreads();
  }

  float lsum = 0.f;
#pragma unroll
  for (int i = 0; i < 4; ++i) {
    int s = s0 + ty * 4 + i;
    float pos = posl[dir * 65536 + b * 1024 + s];  // already *10
    float lg[4];
    float mloc = -INFINITY;
#pragma unroll
    for (int j = 0; j < 4; ++j) {
      int jg = tx * 4 + j;
      lg[j] = (jg == b) ? -INFINITY : acc[i][j] * TEMP_INV;
      mloc = fmaxf(mloc, lg[j]);
    }
#pragma unroll
    for (int mask = 1; mask <= 8; mask <<= 1) mloc = fmaxf(mloc, __shfl_xor(mloc, mask));
    float m = fmaxf(mloc, pos);
    float e = 0.f;
#pragma unroll
    for (int j = 0; j < 4; ++j) e += __expf(lg[j] - m);
#pragma unroll
    for (int mask = 1; mask <= 8; mask <<= 1) e += __shfl_xor(e, mask);
    if (tx == 0) lsum += m + __logf(e + __expf(pos - m)) - pos;
  }
  if (tx == 0) red[ty] = lsum;
  __syncthreads();
  if (tid == 0) {
    float v = 0.f;
#pragma unroll
    for (int r = 0; r < 16; ++r) v += red[r];
    atomicAdd(dsum, v);
  }
}

__global__ void kfinal(const float* __restrict__ gsum, const float* __restrict__ dsum,
                       const int* __restrict__ epoch, float* __restrict__ out) {
  if (threadIdx.x == 0) {
    float g = gsum[0] / 128.0f;
    float dn = dsum[0] / 131072.0f;
    out[0] = (epoch[0] > 0) ? (0.5f * g + 0.5f * dn) : g;  // WARMUP=0, COEFF=0.5
  }
}

// ---------- launch ----------
extern "C" void kernel_launch(void* const* d_in, const int* in_sizes, int n_in,
                              void* d_out, int out_size, void* d_ws, size_t ws_size,
                              hipStream_t stream) {
  const float* ofq = (const float*)d_in[0];
  const float* agq = (const float*)d_in[1];
  const float* xq  = (const float*)d_in[2];
  const float* adq = (const float*)d_in[3];
  const float* ofk = (const float*)d_in[4];
  const float* agk = (const float*)d_in[5];
  const float* xk  = (const float*)d_in[6];
  const float* adk = (const float*)d_in[7];
  const int* epoch = (const int*)d_in[8];
  float* out = (float*)d_out;

  char* wsb = (char*)d_ws;
  __bf16* ofT = (__bf16*)wsb;                       // 64MB
  u64* best_row = (u64*)(wsb + 67108864);           // 512KB
  u64* best_col = best_row + 65536;                 // 512KB
  float* gsum = (float*)(best_col + 65536);
  float* dsum = gsum + 1;
  float* posl = dsum + 1;                           // 512KB
  float* x_invn  = posl + 131072;                   // 512KB (written by kpos)
  float* of_invn = x_invn + 131072;                 // 512KB
  float* adt = of_invn + 131072;                    // 64KB

  // zero best arrays (packed 0 < any real key) + gsum + dsum in one memset
  hipMemsetAsync(best_row, 0, 65536ull * 8 * 2 + 8, stream);

  kcvt<<<4224, 256, 0, stream>>>(ofq, ofk, ofT, of_invn, adq, adk, adt, agq, agk, gsum);

  // ksim split into two half-dispatches (visibility: drops top-5 threshold to ~45us)
  dim3 gs(4, 4, 32);
  ksim<<<gs, 512, 0, stream>>>(ofT, of_invn, best_row, best_col, 0);
  ksim<<<gs, 512, 0, stream>>>(ofT, of_invn, best_row, best_col, 512);

  dim3 gp(64, 2);
  kpos<<<gp, 1024, 0, stream>>>(xq, xk, x_invn, best_row, best_col, posl);

  dim3 gn(16, 64, 2);
  kneg<<<gn, 256, 0, stream>>>(xq, xk, x_invn, adt, posl, dsum);

  kfinal<<<1, 1, 0, stream>>>(gsum, dsum, epoch, out);
}